// Round 8
// baseline (309.031 us; speedup 1.0000x reference)
//
#include <hip/hip_runtime.h>

#define NN 10000
#define EE 320000
#define ET (EE + NN)      // 330000 edges incl self-loops
#define FIN 256
#define HD 128
#define NEG 0.2f
#define CAPS 7            // log2 bucket capacity
#define CAP (1 << CAPS)   // 128 slots/node; max degree ~Poisson(32)+1 << 128

#define GB1 625                     // gemm1 blocks in fused K1 (NN/16)
#define GSC ((ET + 255) / 256)      // 1290 scatter blocks

// Inputs fp32, edge_index int32, OUTPUT fp32.
// HW law (rounds 3+5): NO device-scope fences / grid.sync mid-pipeline on MI355X —
// per-XCD L2s are non-coherent; release/acquire = L2 flush storm (fence: 230 µs;
// grid.sync x7: 978 µs). Kernel-launch boundaries are the cheap sync primitive.
// r6: aggs not chain-latency-bound. r7: padded buckets killed scan+scatter (-13 µs).
// r8: agg1->gemm2 is ROW-LOCAL -> fuse into one kernel (LDS tile, no g1 round-trip).
// Trap: fused kernel must write h2/a_s2/a_d2 (NOT h/a_s/a_d) - other blocks still
// read layer-1 arrays during their phase A.

// ---------------- K1: gemm1 (blocks 0..624) || bucket-scatter (blocks 625..) ----------

__global__ __launch_bounds__(256) void k_gemm1_scatter(
        const float* __restrict__ x, const float* __restrict__ W,
        const float* __restrict__ atts, const float* __restrict__ attd,
        float* __restrict__ h, float* __restrict__ a_s, float* __restrict__ a_d,
        const int* __restrict__ ei, int* __restrict__ counts, int* __restrict__ srclist) {
    __shared__ float xs[16 * FIN];   // 16 KB (unused by scatter blocks)
    int t = threadIdx.x;

    if (blockIdx.x >= GB1) {
        int i = (blockIdx.x - GB1) * 256 + t;
        if (i < ET) {
            int s, d;
            if (i < EE) { s = ei[i]; d = ei[EE + i]; }
            else        { s = i - EE; d = s; }
            int pos = atomicAdd(&counts[d], 1);
            srclist[(d << CAPS) + pos] = s;
        }
        return;
    }

    int m0 = blockIdx.x * 16;
    const float4* xv = (const float4*)(x + (size_t)m0 * FIN);
    float4* xsv = (float4*)xs;
    #pragma unroll
    for (int i = 0; i < 4; i++)      // 16*256/4 = 1024 float4 / 256 threads
        xsv[t + 256 * i] = xv[t + 256 * i];
    __syncthreads();

    int g = t >> 6;
    int tt = t & 63;
    int f = tt * 2;
    const float* xg = xs + g * 4 * FIN;

    float2 acc[4];
    #pragma unroll
    for (int m = 0; m < 4; m++) acc[m] = make_float2(0.f, 0.f);

    for (int k = 0; k < FIN; k += 4) {
        float2 w0 = *(const float2*)&W[(k + 0) * HD + f];
        float2 w1 = *(const float2*)&W[(k + 1) * HD + f];
        float2 w2 = *(const float2*)&W[(k + 2) * HD + f];
        float2 w3 = *(const float2*)&W[(k + 3) * HD + f];
        #pragma unroll
        for (int m = 0; m < 4; m++) {
            float4 xk = *(const float4*)&xg[m * FIN + k];
            acc[m].x += xk.x * w0.x; acc[m].y += xk.x * w0.y;
            acc[m].x += xk.y * w1.x; acc[m].y += xk.y * w1.y;
            acc[m].x += xk.z * w2.x; acc[m].y += xk.z * w2.y;
            acc[m].x += xk.w * w3.x; acc[m].y += xk.w * w3.y;
        }
    }

    float2 ats = *(const float2*)&atts[f];
    float2 atd = *(const float2*)&attd[f];
    #pragma unroll
    for (int m = 0; m < 4; m++) {
        int node = m0 + g * 4 + m;
        *(float2*)&h[(size_t)node * HD + f] = acc[m];
        float vs = acc[m].x * ats.x + acc[m].y * ats.y;
        float vd = acc[m].x * atd.x + acc[m].y * atd.y;
        #pragma unroll
        for (int off = 32; off > 0; off >>= 1) {
            vs += __shfl_down(vs, off);
            vd += __shfl_down(vd, off);
        }
        if (tt == 0) { a_s[node] = vs; a_d[node] = vd; }
    }
}

__device__ __forceinline__ float edge_w(float as_v, float adn) {
    float e = as_v + adn;
    e = (e > 0.f) ? e : NEG * e;
    return __expf(e);
}

// ---------------- K2: agg1 (16 nodes -> LDS tile) + gemm2 (tile @ W2), fused ----------
// Phase A: 16 teams x 32 lanes; lane q owns float4 q of its node's row. srclist/a_s
// loads are team-uniform (HW broadcast); z redundant per lane (no reduction).
// Phase B: 8 wave-groups x 2 nodes, proven gemm structure, x read from LDS.

__global__ __launch_bounds__(512) void k_agg1_gemm2(
        const int* __restrict__ counts, const int* __restrict__ srclist,
        const float* __restrict__ a_s, const float* __restrict__ a_d,
        const float4* __restrict__ h4, const float* __restrict__ b1,
        const float* __restrict__ W2,
        const float* __restrict__ atts2, const float* __restrict__ attd2,
        float* __restrict__ h2, float* __restrict__ a_s2, float* __restrict__ a_d2) {
    __shared__ float gs[16 * HD];    // 8 KB: relu(agg)+b1 tile for 16 nodes
    int t = threadIdx.x;
    int m0 = blockIdx.x * 16;

    // ---- phase A: aggregate ----
    {
        int team = t >> 5, q = t & 31;
        int node = m0 + team;
        int beg = node << CAPS;
        int end = beg + counts[node];
        float adn = a_d[node];
        float4 acc = make_float4(0.f, 0.f, 0.f, 0.f);
        float z = 0.f;
        int p = beg;
        for (; p + 1 < end; p += 2) {
            int s0 = srclist[p], s1 = srclist[p + 1];
            float4 u0 = h4[(size_t)s0 * 32 + q];
            float4 u1 = h4[(size_t)s1 * 32 + q];
            float w0 = edge_w(a_s[s0], adn);
            float w1 = edge_w(a_s[s1], adn);
            z += w0 + w1;
            acc.x += w0 * u0.x + w1 * u1.x;
            acc.y += w0 * u0.y + w1 * u1.y;
            acc.z += w0 * u0.z + w1 * u1.z;
            acc.w += w0 * u0.w + w1 * u1.w;
        }
        if (p < end) {
            int s0 = srclist[p];
            float4 u0 = h4[(size_t)s0 * 32 + q];
            float w0 = edge_w(a_s[s0], adn);
            z += w0;
            acc.x += w0 * u0.x; acc.y += w0 * u0.y;
            acc.z += w0 * u0.z; acc.w += w0 * u0.w;
        }
        float4 b = ((const float4*)b1)[q];
        float4 o;
        o.x = acc.x / z + b.x; o.x = (o.x > 0.f) ? o.x : 0.f;
        o.y = acc.y / z + b.y; o.y = (o.y > 0.f) ? o.y : 0.f;
        o.z = acc.z / z + b.z; o.z = (o.z > 0.f) ? o.z : 0.f;
        o.w = acc.w / z + b.w; o.w = (o.w > 0.f) ? o.w : 0.f;
        *(float4*)&gs[team * HD + q * 4] = o;
    }
    __syncthreads();

    // ---- phase B: gemm 16x128 @ 128x128 ----
    int g = t >> 6;                  // 8 wave-groups, 2 nodes each
    int tt = t & 63;
    int f = tt * 2;
    const float* xg = gs + g * 2 * HD;

    float2 acc[2];
    acc[0] = make_float2(0.f, 0.f);
    acc[1] = make_float2(0.f, 0.f);

    for (int k = 0; k < HD; k += 4) {
        float2 w0 = *(const float2*)&W2[(k + 0) * HD + f];
        float2 w1 = *(const float2*)&W2[(k + 1) * HD + f];
        float2 w2 = *(const float2*)&W2[(k + 2) * HD + f];
        float2 w3 = *(const float2*)&W2[(k + 3) * HD + f];
        #pragma unroll
        for (int m = 0; m < 2; m++) {
            float4 xk = *(const float4*)&xg[m * HD + k];
            acc[m].x += xk.x * w0.x; acc[m].y += xk.x * w0.y;
            acc[m].x += xk.y * w1.x; acc[m].y += xk.y * w1.y;
            acc[m].x += xk.z * w2.x; acc[m].y += xk.z * w2.y;
            acc[m].x += xk.w * w3.x; acc[m].y += xk.w * w3.y;
        }
    }

    float2 ats = *(const float2*)&atts2[f];
    float2 atd = *(const float2*)&attd2[f];
    #pragma unroll
    for (int m = 0; m < 2; m++) {
        int node = m0 + g * 2 + m;
        *(float2*)&h2[(size_t)node * HD + f] = acc[m];
        float vs = acc[m].x * ats.x + acc[m].y * ats.y;
        float vd = acc[m].x * atd.x + acc[m].y * atd.y;
        #pragma unroll
        for (int off = 32; off > 0; off >>= 1) {
            vs += __shfl_down(vs, off);
            vd += __shfl_down(vd, off);
        }
        if (tt == 0) { a_s2[node] = vs; a_d2[node] = vd; }
    }
}

// ---------------- agg2 + reduce_dim fused: r[n] = relu(agg+b2) . Wr + br --------------

__global__ void k_agg2(const int* __restrict__ counts,
                       const int* __restrict__ srclist,
                       const float* __restrict__ a_s,
                       const float* __restrict__ a_d,
                       const float4* __restrict__ h4,
                       const float* __restrict__ bias,
                       const float* __restrict__ Wr,
                       const float* __restrict__ br,
                       float* __restrict__ r) {
    __shared__ float accs[4][HD];
    __shared__ float zs[4];
    __shared__ float red[2];
    int node = blockIdx.x;
    int t = threadIdx.x;
    int slot = t >> 5, q = t & 31;
    int beg = node << CAPS;
    int end = beg + counts[node];
    float adn = a_d[node];
    float4 acc = make_float4(0.f, 0.f, 0.f, 0.f);
    float z = 0.f;
    int p = beg + slot;
    for (; p + 4 < end; p += 8) {
        int s0 = srclist[p];
        int s1 = srclist[p + 4];
        float4 h0 = h4[(size_t)s0 * 32 + q];
        float4 h1 = h4[(size_t)s1 * 32 + q];
        float w0 = edge_w(a_s[s0], adn);
        float w1 = edge_w(a_s[s1], adn);
        z += w0 + w1;
        acc.x += w0 * h0.x + w1 * h1.x;
        acc.y += w0 * h0.y + w1 * h1.y;
        acc.z += w0 * h0.z + w1 * h1.z;
        acc.w += w0 * h0.w + w1 * h1.w;
    }
    if (p < end) {
        int s0 = srclist[p];
        float4 h0 = h4[(size_t)s0 * 32 + q];
        float w0 = edge_w(a_s[s0], adn);
        z += w0;
        acc.x += w0 * h0.x; acc.y += w0 * h0.y;
        acc.z += w0 * h0.z; acc.w += w0 * h0.w;
    }
    *(float4*)&accs[slot][q * 4] = acc;
    if (q == 0) zs[slot] = z;
    __syncthreads();
    float v = accs[0][t] + accs[1][t] + accs[2][t] + accs[3][t];
    float zz = zs[0] + zs[1] + zs[2] + zs[3];
    float o = v / zz + bias[t];
    o = (o > 0.f) ? o : 0.f;
    float part = o * Wr[t];
    #pragma unroll
    for (int off = 32; off > 0; off >>= 1) part += __shfl_down(part, off);
    if ((t & 63) == 0) red[t >> 6] = part;
    __syncthreads();
    if (t == 0) r[node] = red[0] + red[1] + br[0];
}

// ---------------- classifier: out[c] = sum_n r[n]*Wc[n,c] + bc[c] ----------------

__global__ __launch_bounds__(1024) void k_cls(const float* __restrict__ r,
                      const float* __restrict__ Wc,
                      const float* __restrict__ bc,
                      float* __restrict__ out) {
    __shared__ float red0[16], red1[16];
    int t = threadIdx.x;
    float c0 = 0.f, c1 = 0.f;
    for (int n = t; n < NN; n += 1024) {
        float rv = r[n];
        c0 += rv * Wc[2 * n];
        c1 += rv * Wc[2 * n + 1];
    }
    #pragma unroll
    for (int off = 32; off > 0; off >>= 1) {
        c0 += __shfl_down(c0, off);
        c1 += __shfl_down(c1, off);
    }
    if ((t & 63) == 0) { red0[t >> 6] = c0; red1[t >> 6] = c1; }
    __syncthreads();
    if (t == 0) {
        float s0 = bc[0], s1 = bc[1];
        #pragma unroll
        for (int i = 0; i < 16; i++) { s0 += red0[i]; s1 += red1[i]; }
        out[0] = s0;
        out[1] = s1;
    }
}

// ---------------- launch: 5 dispatches, all boundaries are true data deps -------------

extern "C" void kernel_launch(void* const* d_in, const int* in_sizes, int n_in,
                              void* d_out, int out_size, void* d_ws, size_t ws_size,
                              hipStream_t stream) {
    const float* x    = (const float*)d_in[0];
    const int*   ei   = (const int*)d_in[1];
    const float* W1   = (const float*)d_in[2];
    const float* as1  = (const float*)d_in[3];
    const float* ad1  = (const float*)d_in[4];
    const float* b1   = (const float*)d_in[5];
    const float* W2   = (const float*)d_in[6];
    const float* as2  = (const float*)d_in[7];
    const float* ad2  = (const float*)d_in[8];
    const float* b2   = (const float*)d_in[9];
    const float* Wr   = (const float*)d_in[10];
    const float* br   = (const float*)d_in[11];
    const float* Wc   = (const float*)d_in[12];
    const float* bc   = (const float*)d_in[13];
    float* out = (float*)d_out;

    // workspace layout
    float* h     = (float*)d_ws;                 // NN*HD
    float* h2    = h + (size_t)NN * HD;          // NN*HD
    float* a_s   = h2 + (size_t)NN * HD;         // NN  (layer-1)
    float* a_d   = a_s + NN;                     // NN  (layer-1)
    float* as2w  = a_d + NN;                     // NN  (layer-2)
    float* ad2w  = as2w + NN;                    // NN  (layer-2)
    float* r     = ad2w + NN;                    // NN
    int* counts  = (int*)(r + NN);               // NN
    int* srclist = counts + NN;                  // NN*CAP (5.12 MB)

    hipMemsetAsync(counts, 0, NN * sizeof(int), stream);

    // K1: gemm1 || bucket-scatter
    k_gemm1_scatter<<<GB1 + GSC, 256, 0, stream>>>(x, W1, as1, ad1, h, a_s, a_d,
                                                   ei, counts, srclist);
    // K2: agg1 + gemm2 fused (row-local)
    k_agg1_gemm2<<<GB1, 512, 0, stream>>>(counts, srclist, a_s, a_d,
                                          (const float4*)h, b1, W2, as2, ad2,
                                          h2, as2w, ad2w);
    // K3: agg2 + reduce_dim
    k_agg2<<<NN, 128, 0, stream>>>(counts, srclist, as2w, ad2w,
                                   (const float4*)h2, b2, Wr, br, r);
    // K4: classifier
    k_cls<<<1, 1024, 0, stream>>>(r, Wc, bc, out);
}

// Round 9
// 192.625 us; speedup vs baseline: 1.6043x; 1.6043x over previous
//
#include <hip/hip_runtime.h>

#define NN 10000
#define EE 320000
#define ET (EE + NN)      // 330000 edges incl self-loops
#define FIN 256
#define HD 128
#define NEG 0.2f
#define CAPS 7            // log2 bucket capacity
#define CAP (1 << CAPS)   // 128 slots/node; max degree ~Poisson(32)+1 << 128

#define GB1 625                     // gemm1 blocks in fused K1 (NN/16)
#define GSC ((ET + 255) / 256)      // 1290 scatter blocks

// Inputs fp32, edge_index int32, OUTPUT fp32.
// HW laws learned (rounds 3,5,8):
//  - NO device-scope fences / grid.sync mid-pipeline (per-XCD L2s non-coherent;
//    release/acquire = L2 flush storm: 230 µs / 978 µs disasters). Launch boundaries
//    are the cheap sync.
//  - Aggregation gathers need ~10000 blocks for latency hiding (625-block fused
//    version: 169 µs, occupancy 18%).
//  - h (5.12 MB) > 4 MB XCD L2 -> full-row gathers thrash (140 MB fetch measured r8).
// r9: plane-major h [2][NN][64]; each agg block gathers ONE 2.56 MB half-plane
// (L2-resident). Blocks 0..NN-1 = plane 0, NN..2NN-1 = plane 1 (time-separated by
// launch order). Outputs per plane go to disjoint addresses — no cross-block deps.

// ---------------- K1: gemm1 (blocks 0..624) || bucket-scatter (blocks 625..) ----------

__global__ __launch_bounds__(256) void k_gemm1_scatter(
        const float* __restrict__ x, const float* __restrict__ W,
        const float* __restrict__ atts, const float* __restrict__ attd,
        float* __restrict__ h, float* __restrict__ a_s, float* __restrict__ a_d,
        const int* __restrict__ ei, int* __restrict__ counts, int* __restrict__ srclist) {
    __shared__ float xs[16 * FIN];   // 16 KB (unused by scatter blocks)
    int t = threadIdx.x;

    if (blockIdx.x >= GB1) {
        int i = (blockIdx.x - GB1) * 256 + t;
        if (i < ET) {
            int s, d;
            if (i < EE) { s = ei[i]; d = ei[EE + i]; }
            else        { s = i - EE; d = s; }
            int pos = atomicAdd(&counts[d], 1);
            srclist[(d << CAPS) + pos] = s;
        }
        return;
    }

    int m0 = blockIdx.x * 16;
    const float4* xv = (const float4*)(x + (size_t)m0 * FIN);
    float4* xsv = (float4*)xs;
    #pragma unroll
    for (int i = 0; i < 4; i++)      // 16*256/4 = 1024 float4 / 256 threads
        xsv[t + 256 * i] = xv[t + 256 * i];
    __syncthreads();

    int g = t >> 6;
    int tt = t & 63;
    int f = tt * 2;
    const float* xg = xs + g * 4 * FIN;

    float2 acc[4];
    #pragma unroll
    for (int m = 0; m < 4; m++) acc[m] = make_float2(0.f, 0.f);

    for (int k = 0; k < FIN; k += 4) {
        float2 w0 = *(const float2*)&W[(k + 0) * HD + f];
        float2 w1 = *(const float2*)&W[(k + 1) * HD + f];
        float2 w2 = *(const float2*)&W[(k + 2) * HD + f];
        float2 w3 = *(const float2*)&W[(k + 3) * HD + f];
        #pragma unroll
        for (int m = 0; m < 4; m++) {
            float4 xk = *(const float4*)&xg[m * FIN + k];
            acc[m].x += xk.x * w0.x; acc[m].y += xk.x * w0.y;
            acc[m].x += xk.y * w1.x; acc[m].y += xk.y * w1.y;
            acc[m].x += xk.z * w2.x; acc[m].y += xk.z * w2.y;
            acc[m].x += xk.w * w3.x; acc[m].y += xk.w * w3.y;
        }
    }

    // write h PLANE-MAJOR: plane = f/64, local feature = f%64
    float* hw = h + (size_t)(f >> 6) * NN * 64 + (f & 63);
    float2 ats = *(const float2*)&atts[f];
    float2 atd = *(const float2*)&attd[f];
    #pragma unroll
    for (int m = 0; m < 4; m++) {
        int node = m0 + g * 4 + m;
        *(float2*)&hw[(size_t)node * 64] = acc[m];
        float vs = acc[m].x * ats.x + acc[m].y * ats.y;
        float vd = acc[m].x * atd.x + acc[m].y * atd.y;
        #pragma unroll
        for (int off = 32; off > 0; off >>= 1) {
            vs += __shfl_down(vs, off);
            vd += __shfl_down(vd, off);
        }
        if (tt == 0) { a_s[node] = vs; a_d[node] = vd; }
    }
}

__device__ __forceinline__ float edge_w(float as_v, float adn) {
    float e = as_v + adn;
    e = (e > 0.f) ? e : NEG * e;
    return __expf(e);
}

// ---------------- aggregation: block per (plane, node); 4 slots x 32 lanes ------------
// Lane q owns float2 q of the 64-feature half-plane row (256 B coalesced per edge).
// DOWR=false: write g1[node][plane*64+t] (relu(agg+b)). DOWR=true: write
// rpart[plane*NN+node] = (relu half) . Wr[plane half]  (bias br added in cls).

template<bool DOWR>
__global__ __launch_bounds__(128) void k_agg(
        const int* __restrict__ counts, const int* __restrict__ srclist,
        const float* __restrict__ a_s, const float* __restrict__ a_d,
        const float* __restrict__ hplanes,   // [2][NN][64]
        const float* __restrict__ bias,      // [128]
        const float* __restrict__ Wr,        // [128] (used iff DOWR)
        float* __restrict__ outv) {          // g1 [NN][128] or rpart [2][NN]
    __shared__ float accs[4][64];
    __shared__ float zs[4];
    int bid = blockIdx.x;
    int plane = (bid >= NN) ? 1 : 0;
    int node = bid - plane * NN;
    int t = threadIdx.x;
    int slot = t >> 5, q = t & 31;
    int beg = node << CAPS;
    int end = beg + counts[node];
    float adn = a_d[node];
    const float2* hp = (const float2*)(hplanes + (size_t)plane * NN * 64);
    float2 acc = make_float2(0.f, 0.f);
    float z = 0.f;
    int p = beg + slot;
    for (; p + 4 < end; p += 8) {
        int s0 = srclist[p];
        int s1 = srclist[p + 4];
        float2 v0 = hp[(size_t)s0 * 32 + q];
        float2 v1 = hp[(size_t)s1 * 32 + q];
        float w0 = edge_w(a_s[s0], adn);
        float w1 = edge_w(a_s[s1], adn);
        z += w0 + w1;
        acc.x += w0 * v0.x + w1 * v1.x;
        acc.y += w0 * v0.y + w1 * v1.y;
    }
    if (p < end) {
        int s0 = srclist[p];
        float2 v0 = hp[(size_t)s0 * 32 + q];
        float w0 = edge_w(a_s[s0], adn);
        z += w0;
        acc.x += w0 * v0.x;
        acc.y += w0 * v0.y;
    }
    *(float2*)&accs[slot][q * 2] = acc;
    if (q == 0) zs[slot] = z;
    __syncthreads();
    if (t < 64) {
        float v = accs[0][t] + accs[1][t] + accs[2][t] + accs[3][t];
        float zz = zs[0] + zs[1] + zs[2] + zs[3];
        float o = v / zz + bias[plane * 64 + t];
        o = (o > 0.f) ? o : 0.f;
        if (!DOWR) {
            outv[(size_t)node * HD + plane * 64 + t] = o;
        } else {
            float part = o * Wr[plane * 64 + t];
            #pragma unroll
            for (int off = 32; off > 0; off >>= 1) part += __shfl_down(part, off);
            if (t == 0) outv[(size_t)plane * NN + node] = part;
        }
    }
}

// ---------------- GEMM layer 2: h2 = g1 @ W2 (K=128), h2 written plane-major ----------

__global__ __launch_bounds__(256) void k_gemm2(const float* __restrict__ x,
                        const float* __restrict__ W,
                        const float* __restrict__ atts,
                        const float* __restrict__ attd,
                        float* __restrict__ h,
                        float* __restrict__ a_s,
                        float* __restrict__ a_d) {
    __shared__ float xs[16 * HD];
    int t = threadIdx.x;
    int m0 = blockIdx.x * 16;
    const float4* xv = (const float4*)(x + (size_t)m0 * HD);
    float4* xsv = (float4*)xs;
    #pragma unroll
    for (int i = 0; i < 2; i++)
        xsv[t + 256 * i] = xv[t + 256 * i];
    __syncthreads();

    int g = t >> 6;
    int tt = t & 63;
    int f = tt * 2;
    const float* xg = xs + g * 4 * HD;

    float2 acc[4];
    #pragma unroll
    for (int m = 0; m < 4; m++) acc[m] = make_float2(0.f, 0.f);

    for (int k = 0; k < HD; k += 4) {
        float2 w0 = *(const float2*)&W[(k + 0) * HD + f];
        float2 w1 = *(const float2*)&W[(k + 1) * HD + f];
        float2 w2 = *(const float2*)&W[(k + 2) * HD + f];
        float2 w3 = *(const float2*)&W[(k + 3) * HD + f];
        #pragma unroll
        for (int m = 0; m < 4; m++) {
            float4 xk = *(const float4*)&xg[m * HD + k];
            acc[m].x += xk.x * w0.x; acc[m].y += xk.x * w0.y;
            acc[m].x += xk.y * w1.x; acc[m].y += xk.y * w1.y;
            acc[m].x += xk.z * w2.x; acc[m].y += xk.z * w2.y;
            acc[m].x += xk.w * w3.x; acc[m].y += xk.w * w3.y;
        }
    }

    float* hw = h + (size_t)(f >> 6) * NN * 64 + (f & 63);
    float2 ats = *(const float2*)&atts[f];
    float2 atd = *(const float2*)&attd[f];
    #pragma unroll
    for (int m = 0; m < 4; m++) {
        int node = m0 + g * 4 + m;
        *(float2*)&hw[(size_t)node * 64] = acc[m];
        float vs = acc[m].x * ats.x + acc[m].y * ats.y;
        float vd = acc[m].x * atd.x + acc[m].y * atd.y;
        #pragma unroll
        for (int off = 32; off > 0; off >>= 1) {
            vs += __shfl_down(vs, off);
            vd += __shfl_down(vd, off);
        }
        if (tt == 0) { a_s[node] = vs; a_d[node] = vd; }
    }
}

// ---------------- classifier: rv[n] = rpart0[n]+rpart1[n]+br; out = rv @ Wc + bc ------

__global__ __launch_bounds__(1024) void k_cls(const float* __restrict__ rp,
                      const float* __restrict__ Wc,
                      const float* __restrict__ bc,
                      const float* __restrict__ br,
                      float* __restrict__ out) {
    __shared__ float red0[16], red1[16];
    int t = threadIdx.x;
    float br0 = br[0];
    float c0 = 0.f, c1 = 0.f;
    for (int n = t; n < NN; n += 1024) {
        float rv = rp[n] + rp[NN + n] + br0;
        c0 += rv * Wc[2 * n];
        c1 += rv * Wc[2 * n + 1];
    }
    #pragma unroll
    for (int off = 32; off > 0; off >>= 1) {
        c0 += __shfl_down(c0, off);
        c1 += __shfl_down(c1, off);
    }
    if ((t & 63) == 0) { red0[t >> 6] = c0; red1[t >> 6] = c1; }
    __syncthreads();
    if (t == 0) {
        float s0 = bc[0], s1 = bc[1];
        #pragma unroll
        for (int i = 0; i < 16; i++) { s0 += red0[i]; s1 += red1[i]; }
        out[0] = s0;
        out[1] = s1;
    }
}

// ---------------- launch: 6 dispatches, all boundaries are true data deps -------------

extern "C" void kernel_launch(void* const* d_in, const int* in_sizes, int n_in,
                              void* d_out, int out_size, void* d_ws, size_t ws_size,
                              hipStream_t stream) {
    const float* x    = (const float*)d_in[0];
    const int*   ei   = (const int*)d_in[1];
    const float* W1   = (const float*)d_in[2];
    const float* as1  = (const float*)d_in[3];
    const float* ad1  = (const float*)d_in[4];
    const float* b1   = (const float*)d_in[5];
    const float* W2   = (const float*)d_in[6];
    const float* as2  = (const float*)d_in[7];
    const float* ad2  = (const float*)d_in[8];
    const float* b2   = (const float*)d_in[9];
    const float* Wr   = (const float*)d_in[10];
    const float* br   = (const float*)d_in[11];
    const float* Wc   = (const float*)d_in[12];
    const float* bc   = (const float*)d_in[13];
    float* out = (float*)d_out;

    // workspace layout
    float* h     = (float*)d_ws;                 // NN*HD, plane-major [2][NN][64]
    float* g1    = h + (size_t)NN * HD;          // NN*HD, row-major
    float* a_s   = g1 + (size_t)NN * HD;         // NN (layer-1, then reused layer-2)
    float* a_d   = a_s + NN;                     // NN
    float* rp    = a_d + NN;                     // 2*NN (per-plane partial r)
    int* counts  = (int*)(rp + 2 * NN);          // NN
    int* srclist = counts + NN;                  // NN*CAP (5.12 MB)

    hipMemsetAsync(counts, 0, NN * sizeof(int), stream);

    // K1: gemm1 || bucket-scatter (h plane-major)
    k_gemm1_scatter<<<GB1 + GSC, 256, 0, stream>>>(x, W1, as1, ad1, h, a_s, a_d,
                                                   ei, counts, srclist);
    // K2: agg1 over half-planes (plane 0 blocks first, then plane 1)
    k_agg<false><<<2 * NN, 128, 0, stream>>>(counts, srclist, a_s, a_d,
                                             h, b1, nullptr, g1);
    // K3: gemm2 (reads g1 row-major, writes h plane-major; overwrites a_s/a_d)
    k_gemm2<<<GB1, 256, 0, stream>>>(g1, W2, as2, ad2, h, a_s, a_d);
    // K4: agg2 + reduce_dim partials per plane
    k_agg<true><<<2 * NN, 128, 0, stream>>>(counts, srclist, a_s, a_d,
                                            h, b2, Wr, rp);
    // K5: classifier (sums plane partials + br)
    k_cls<<<1, 1024, 0, stream>>>(rp, Wc, bc, br, out);
}

// Round 11
// 179.744 us; speedup vs baseline: 1.7193x; 1.0717x over previous
//
#include <hip/hip_runtime.h>

#define NN 10000
#define EE 320000
#define ET (EE + NN)      // 330000 edges incl self-loops
#define FIN 256
#define HD 128
#define NEG 0.2f
#define CAPS 7            // log2 bucket capacity
#define CAP (1 << CAPS)   // 128 slots/node; max degree ~Poisson(32)+1 << 128

#define GB1 625                     // gemm1 blocks in fused K1 (NN/16)
#define GSC ((ET + 255) / 256)      // 1290 scatter blocks

// Inputs fp32, edge_index int32, OUTPUT fp32.
// ===== Session laws (measured, rounds 3-9) =====
//  - NO device-scope fences / grid.sync mid-pipeline on MI355X: per-XCD L2s are
//    non-coherent; release/acquire = L2 flush storm (r3 fence: 230 µs kernel;
//    r5 grid.sync x7: 978 µs kernel). Kernel-launch boundaries are the cheap sync.
//  - Aggregation kernels (block-per-node, 4 slots x 32 lanes, float4 gathers) are at
//    their service floor: 8-slot variant = null (r6), 625-block fused variant
//    thrashes (r8: 140 MB fetch, 18% occ), half-plane split regresses (r9: +13 µs).
//  - Padded per-node buckets (128 slots) beat scan+rank CSR: -13 µs (r7).
//  - gemm1 || scatter block-range fusion hides ~13 µs of atomic latency (r4).
//  - Fixed harness floor ~76 µs (fill 44 µs + launch/sync), measured as r5 residue.
// This file == round-7 state, the proven minimum (179.7 µs). Round-10 bench was an
// infrastructure failure (container), not a kernel failure — resubmitted unchanged.

// ---------------- K1: gemm1 (blocks 0..624) || bucket-scatter (blocks 625..) ----------

__global__ __launch_bounds__(256) void k_gemm1_scatter(
        const float* __restrict__ x, const float* __restrict__ W,
        const float* __restrict__ atts, const float* __restrict__ attd,
        float* __restrict__ h, float* __restrict__ a_s, float* __restrict__ a_d,
        const int* __restrict__ ei, int* __restrict__ counts, int* __restrict__ srclist) {
    __shared__ float xs[16 * FIN];   // 16 KB (unused by scatter blocks)
    int t = threadIdx.x;

    if (blockIdx.x >= GB1) {
        int i = (blockIdx.x - GB1) * 256 + t;
        if (i < ET) {
            int s, d;
            if (i < EE) { s = ei[i]; d = ei[EE + i]; }
            else        { s = i - EE; d = s; }
            int pos = atomicAdd(&counts[d], 1);
            srclist[(d << CAPS) + pos] = s;
        }
        return;
    }

    int m0 = blockIdx.x * 16;
    const float4* xv = (const float4*)(x + (size_t)m0 * FIN);
    float4* xsv = (float4*)xs;
    #pragma unroll
    for (int i = 0; i < 4; i++)      // 16*256/4 = 1024 float4 / 256 threads
        xsv[t + 256 * i] = xv[t + 256 * i];
    __syncthreads();

    int g = t >> 6;
    int tt = t & 63;
    int f = tt * 2;
    const float* xg = xs + g * 4 * FIN;

    float2 acc[4];
    #pragma unroll
    for (int m = 0; m < 4; m++) acc[m] = make_float2(0.f, 0.f);

    for (int k = 0; k < FIN; k += 4) {
        float2 w0 = *(const float2*)&W[(k + 0) * HD + f];
        float2 w1 = *(const float2*)&W[(k + 1) * HD + f];
        float2 w2 = *(const float2*)&W[(k + 2) * HD + f];
        float2 w3 = *(const float2*)&W[(k + 3) * HD + f];
        #pragma unroll
        for (int m = 0; m < 4; m++) {
            float4 xk = *(const float4*)&xg[m * FIN + k];
            acc[m].x += xk.x * w0.x; acc[m].y += xk.x * w0.y;
            acc[m].x += xk.y * w1.x; acc[m].y += xk.y * w1.y;
            acc[m].x += xk.z * w2.x; acc[m].y += xk.z * w2.y;
            acc[m].x += xk.w * w3.x; acc[m].y += xk.w * w3.y;
        }
    }

    float2 ats = *(const float2*)&atts[f];
    float2 atd = *(const float2*)&attd[f];
    #pragma unroll
    for (int m = 0; m < 4; m++) {
        int node = m0 + g * 4 + m;
        *(float2*)&h[(size_t)node * HD + f] = acc[m];
        float vs = acc[m].x * ats.x + acc[m].y * ats.y;
        float vd = acc[m].x * atd.x + acc[m].y * atd.y;
        #pragma unroll
        for (int off = 32; off > 0; off >>= 1) {
            vs += __shfl_down(vs, off);
            vd += __shfl_down(vd, off);
        }
        if (tt == 0) { a_s[node] = vs; a_d[node] = vd; }
    }
}

// ---------------- aggregation: block per dst node, 4 slots x 32 lanes -----------------
// reads bucket [node*128, node*128 + counts[node])

__device__ __forceinline__ float edge_w(float as_v, float adn) {
    float e = as_v + adn;
    e = (e > 0.f) ? e : NEG * e;
    return __expf(e);
}

__global__ void k_agg1(const int* __restrict__ counts,
                       const int* __restrict__ srclist,
                       const float* __restrict__ a_s,
                       const float* __restrict__ a_d,
                       const float4* __restrict__ h4,
                       const float* __restrict__ bias,
                       float* __restrict__ g) {
    __shared__ float accs[4][HD];
    __shared__ float zs[4];
    int node = blockIdx.x;
    int t = threadIdx.x;
    int slot = t >> 5, q = t & 31;
    int beg = node << CAPS;
    int end = beg + counts[node];
    float adn = a_d[node];
    float4 acc = make_float4(0.f, 0.f, 0.f, 0.f);
    float z = 0.f;
    int p = beg + slot;
    for (; p + 4 < end; p += 8) {
        int s0 = srclist[p];
        int s1 = srclist[p + 4];
        float4 h0 = h4[(size_t)s0 * 32 + q];
        float4 h1 = h4[(size_t)s1 * 32 + q];
        float w0 = edge_w(a_s[s0], adn);
        float w1 = edge_w(a_s[s1], adn);
        z += w0 + w1;
        acc.x += w0 * h0.x + w1 * h1.x;
        acc.y += w0 * h0.y + w1 * h1.y;
        acc.z += w0 * h0.z + w1 * h1.z;
        acc.w += w0 * h0.w + w1 * h1.w;
    }
    if (p < end) {
        int s0 = srclist[p];
        float4 h0 = h4[(size_t)s0 * 32 + q];
        float w0 = edge_w(a_s[s0], adn);
        z += w0;
        acc.x += w0 * h0.x; acc.y += w0 * h0.y;
        acc.z += w0 * h0.z; acc.w += w0 * h0.w;
    }
    *(float4*)&accs[slot][q * 4] = acc;
    if (q == 0) zs[slot] = z;
    __syncthreads();
    float v = accs[0][t] + accs[1][t] + accs[2][t] + accs[3][t];
    float zz = zs[0] + zs[1] + zs[2] + zs[3];
    float o = v / zz + bias[t];
    g[(size_t)node * HD + t] = (o > 0.f) ? o : 0.f;   // relu
}

// ---------------- GEMM layer 2: h = g1 @ W2 (K=128) ----------------

__global__ __launch_bounds__(256) void k_gemm2(const float* __restrict__ x,
                        const float* __restrict__ W,
                        const float* __restrict__ atts,
                        const float* __restrict__ attd,
                        float* __restrict__ h,
                        float* __restrict__ a_s,
                        float* __restrict__ a_d) {
    __shared__ float xs[16 * HD];
    int t = threadIdx.x;
    int m0 = blockIdx.x * 16;
    const float4* xv = (const float4*)(x + (size_t)m0 * HD);
    float4* xsv = (float4*)xs;
    #pragma unroll
    for (int i = 0; i < 2; i++)
        xsv[t + 256 * i] = xv[t + 256 * i];
    __syncthreads();

    int g = t >> 6;
    int tt = t & 63;
    int f = tt * 2;
    const float* xg = xs + g * 4 * HD;

    float2 acc[4];
    #pragma unroll
    for (int m = 0; m < 4; m++) acc[m] = make_float2(0.f, 0.f);

    for (int k = 0; k < HD; k += 4) {
        float2 w0 = *(const float2*)&W[(k + 0) * HD + f];
        float2 w1 = *(const float2*)&W[(k + 1) * HD + f];
        float2 w2 = *(const float2*)&W[(k + 2) * HD + f];
        float2 w3 = *(const float2*)&W[(k + 3) * HD + f];
        #pragma unroll
        for (int m = 0; m < 4; m++) {
            float4 xk = *(const float4*)&xg[m * HD + k];
            acc[m].x += xk.x * w0.x; acc[m].y += xk.x * w0.y;
            acc[m].x += xk.y * w1.x; acc[m].y += xk.y * w1.y;
            acc[m].x += xk.z * w2.x; acc[m].y += xk.z * w2.y;
            acc[m].x += xk.w * w3.x; acc[m].y += xk.w * w3.y;
        }
    }

    float2 ats = *(const float2*)&atts[f];
    float2 atd = *(const float2*)&attd[f];
    #pragma unroll
    for (int m = 0; m < 4; m++) {
        int node = m0 + g * 4 + m;
        *(float2*)&h[(size_t)node * HD + f] = acc[m];
        float vs = acc[m].x * ats.x + acc[m].y * ats.y;
        float vd = acc[m].x * atd.x + acc[m].y * atd.y;
        #pragma unroll
        for (int off = 32; off > 0; off >>= 1) {
            vs += __shfl_down(vs, off);
            vd += __shfl_down(vd, off);
        }
        if (tt == 0) { a_s[node] = vs; a_d[node] = vd; }
    }
}

// ---------------- agg2 + reduce_dim fused: r[n] = relu(agg+b2) . Wr + br --------------

__global__ void k_agg2(const int* __restrict__ counts,
                       const int* __restrict__ srclist,
                       const float* __restrict__ a_s,
                       const float* __restrict__ a_d,
                       const float4* __restrict__ h4,
                       const float* __restrict__ bias,
                       const float* __restrict__ Wr,
                       const float* __restrict__ br,
                       float* __restrict__ r) {
    __shared__ float accs[4][HD];
    __shared__ float zs[4];
    __shared__ float red[2];
    int node = blockIdx.x;
    int t = threadIdx.x;
    int slot = t >> 5, q = t & 31;
    int beg = node << CAPS;
    int end = beg + counts[node];
    float adn = a_d[node];
    float4 acc = make_float4(0.f, 0.f, 0.f, 0.f);
    float z = 0.f;
    int p = beg + slot;
    for (; p + 4 < end; p += 8) {
        int s0 = srclist[p];
        int s1 = srclist[p + 4];
        float4 h0 = h4[(size_t)s0 * 32 + q];
        float4 h1 = h4[(size_t)s1 * 32 + q];
        float w0 = edge_w(a_s[s0], adn);
        float w1 = edge_w(a_s[s1], adn);
        z += w0 + w1;
        acc.x += w0 * h0.x + w1 * h1.x;
        acc.y += w0 * h0.y + w1 * h1.y;
        acc.z += w0 * h0.z + w1 * h1.z;
        acc.w += w0 * h0.w + w1 * h1.w;
    }
    if (p < end) {
        int s0 = srclist[p];
        float4 h0 = h4[(size_t)s0 * 32 + q];
        float w0 = edge_w(a_s[s0], adn);
        z += w0;
        acc.x += w0 * h0.x; acc.y += w0 * h0.y;
        acc.z += w0 * h0.z; acc.w += w0 * h0.w;
    }
    *(float4*)&accs[slot][q * 4] = acc;
    if (q == 0) zs[slot] = z;
    __syncthreads();
    float v = accs[0][t] + accs[1][t] + accs[2][t] + accs[3][t];
    float zz = zs[0] + zs[1] + zs[2] + zs[3];
    float o = v / zz + bias[t];
    o = (o > 0.f) ? o : 0.f;
    float part = o * Wr[t];
    #pragma unroll
    for (int off = 32; off > 0; off >>= 1) part += __shfl_down(part, off);
    if ((t & 63) == 0) red[t >> 6] = part;
    __syncthreads();
    if (t == 0) r[node] = red[0] + red[1] + br[0];
}

// ---------------- classifier: out[c] = sum_n r[n]*Wc[n,c] + bc[c] ----------------

__global__ __launch_bounds__(1024) void k_cls(const float* __restrict__ r,
                      const float* __restrict__ Wc,
                      const float* __restrict__ bc,
                      float* __restrict__ out) {
    __shared__ float red0[16], red1[16];
    int t = threadIdx.x;
    float c0 = 0.f, c1 = 0.f;
    for (int n = t; n < NN; n += 1024) {
        float rv = r[n];
        c0 += rv * Wc[2 * n];
        c1 += rv * Wc[2 * n + 1];
    }
    #pragma unroll
    for (int off = 32; off > 0; off >>= 1) {
        c0 += __shfl_down(c0, off);
        c1 += __shfl_down(c1, off);
    }
    if ((t & 63) == 0) { red0[t >> 6] = c0; red1[t >> 6] = c1; }
    __syncthreads();
    if (t == 0) {
        float s0 = bc[0], s1 = bc[1];
        #pragma unroll
        for (int i = 0; i < 16; i++) { s0 += red0[i]; s1 += red1[i]; }
        out[0] = s0;
        out[1] = s1;
    }
}

// ---------------- launch: 6 dispatches, all boundaries are true data deps -------------

extern "C" void kernel_launch(void* const* d_in, const int* in_sizes, int n_in,
                              void* d_out, int out_size, void* d_ws, size_t ws_size,
                              hipStream_t stream) {
    const float* x    = (const float*)d_in[0];
    const int*   ei   = (const int*)d_in[1];
    const float* W1   = (const float*)d_in[2];
    const float* as1  = (const float*)d_in[3];
    const float* ad1  = (const float*)d_in[4];
    const float* b1   = (const float*)d_in[5];
    const float* W2   = (const float*)d_in[6];
    const float* as2  = (const float*)d_in[7];
    const float* ad2  = (const float*)d_in[8];
    const float* b2   = (const float*)d_in[9];
    const float* Wr   = (const float*)d_in[10];
    const float* br   = (const float*)d_in[11];
    const float* Wc   = (const float*)d_in[12];
    const float* bc   = (const float*)d_in[13];
    float* out = (float*)d_out;

    // workspace layout
    float* h     = (float*)d_ws;                 // NN*HD
    float* g1    = h + (size_t)NN * HD;          // NN*HD
    float* a_s   = g1 + (size_t)NN * HD;         // NN
    float* a_d   = a_s + NN;                     // NN
    float* r     = a_d + NN;                     // NN
    int* counts  = (int*)(r + NN);               // NN
    int* srclist = counts + NN;                  // NN*CAP (5.12 MB)

    hipMemsetAsync(counts, 0, NN * sizeof(int), stream);

    // K1: gemm1 || bucket-scatter
    k_gemm1_scatter<<<GB1 + GSC, 256, 0, stream>>>(x, W1, as1, ad1, h, a_s, a_d,
                                                   ei, counts, srclist);
    // layer 1 aggregation
    k_agg1<<<NN, 128, 0, stream>>>(counts, srclist, a_s, a_d,
                                   (const float4*)h, b1, g1);
    // layer 2
    k_gemm2<<<GB1, 256, 0, stream>>>(g1, W2, as2, ad2, h, a_s, a_d);
    k_agg2<<<NN, 128, 0, stream>>>(counts, srclist, a_s, a_d,
                                   (const float4*)h, b2, Wr, br, r);
    // classifier
    k_cls<<<1, 1024, 0, stream>>>(r, Wc, bc, out);
}